// Round 1
// baseline (343.840 us; speedup 1.0000x reference)
//
#include <hip/hip_runtime.h>
#include <math.h>

// ---------------------------------------------------------------------------
// UltraMem forward, MI355X. Shapes: B=2 N=1024 DIM=1024 DQK=128 NUM_KEYS=256
// TOPK=32 RANK=2 HEADS=2 DV=512 KCONV=5.
// ---------------------------------------------------------------------------

#define ROWS 2048            // B*N
#define NEG_BIG (-1e30f)

// ======================= 2x2 SVD (LAPACK dgesdd replica) ====================
__device__ inline double dsgn(double x, double y) { return (y >= 0.0) ? fabs(x) : -fabs(x); }

__device__ void dlasv2_dev(double f, double g, double h,
                           double& ssmin, double& ssmax,
                           double& snr, double& csr, double& snl, double& csl)
{
  const double EPSD = 2.2204460492503131e-16;
  double ft = f, fa = fabs(f), ht = h, ha = fabs(h);
  int pmax = 1;
  bool swp = (ha > fa);
  if (swp) { pmax = 3; double tp = ft; ft = ht; ht = tp; tp = fa; fa = ha; ha = tp; }
  double gt = g, ga = fabs(gt);
  double clt = 0.0, crt = 0.0, slt = 0.0, srt = 0.0;
  if (ga == 0.0) {
    ssmin = ha; ssmax = fa; clt = 1.0; crt = 1.0; slt = 0.0; srt = 0.0;
  } else {
    bool gasmal = true;
    if (ga > fa) {
      pmax = 2;
      if ((fa / ga) < EPSD) {
        gasmal = false;
        ssmax = ga;
        if (ha > 1.0) ssmin = fa / (ga / ha); else ssmin = (fa / ga) * ha;
        clt = 1.0; slt = ht / gt; srt = 1.0; crt = ft / gt;
      }
    }
    if (gasmal) {
      double dd = fa - ha, l;
      if (dd == fa) l = 1.0; else l = dd / fa;
      double m  = gt / ft;
      double t  = 2.0 - l;
      double mm = m * m, tt = t * t;
      double s  = sqrt(tt + mm);
      double r  = (l == 0.0) ? fabs(m) : sqrt(l * l + mm);
      double a  = 0.5 * (s + r);
      ssmin = ha / a;
      ssmax = fa * a;
      if (mm == 0.0) {
        if (l == 0.0) t = dsgn(2.0, ft) * dsgn(1.0, gt);
        else          t = gt / dsgn(dd, ft) + m / t;
      } else {
        t = (m / (s + t) + m / (r + l)) * (1.0 + a);
      }
      double ll = sqrt(t * t + 4.0);
      crt = 2.0 / ll;
      srt = t / ll;
      clt = (crt + srt * m) / a;
      slt = (ht / ft) * srt / a;
    }
  }
  if (swp) { csl = srt; snl = crt; csr = slt; snr = clt; }
  else     { csl = clt; snl = slt; csr = crt; snr = srt; }
  double tsign = 1.0;
  if (pmax == 1) tsign = dsgn(1.0, csr) * dsgn(1.0, csl) * dsgn(1.0, f);
  if (pmax == 2) tsign = dsgn(1.0, snr) * dsgn(1.0, csl) * dsgn(1.0, g);
  if (pmax == 3) tsign = dsgn(1.0, snr) * dsgn(1.0, snl) * dsgn(1.0, h);
  ssmax = dsgn(ssmax, tsign);
  ssmin = dsgn(ssmin, tsign * dsgn(1.0, f) * dsgn(1.0, h));
}

// misc[0..3] = u_vec[h][r] (U col 0), misc[4..7] = t_vec[h][r] (VT row 0)
__global__ void svd_kernel(const float* __restrict__ core, float* __restrict__ misc,
                           float* __restrict__ aux_out)
{
  if (threadIdx.x != 0 || blockIdx.x != 0) return;
  double aux = 0.0;
  for (int hh = 0; hh < 2; hh++) {
    double a = (double)core[hh * 4 + 0];
    double b = (double)core[hh * 4 + 1];
    double c = (double)core[hh * 4 + 2];
    double d = (double)core[hh * 4 + 3];
    // dgebrd for 2x2: Householder on col 1 (dlarfg convention), P = I.
    double tau = 0.0, v2 = 0.0, d1, e, d2;
    if (c != 0.0) {
      double nrm  = sqrt(a * a + c * c);
      double beta = (a >= 0.0) ? -nrm : nrm;
      tau = (beta - a) / beta;
      v2  = c / (a - beta);
      double wsum = b + v2 * d;
      d1 = beta;
      e  = b - tau * wsum;
      d2 = d - tau * v2 * wsum;
    } else { d1 = a; e = b; d2 = d; }
    double ssmin, ssmax, snr, csr, snl, csl;
    dlasv2_dev(d1, e, d2, ssmin, ssmax, snr, csr, snl, csl);
    // dbdsqr: U2 col0 = [csl, snl]; VT row0 = [csr, snr], negated if ssmax<0.
    // U = H1 * U2, H1 = I - tau*v v^T, v = [1, v2].
    double t0 = csl + v2 * snl;
    double u0 = csl - tau * t0;
    double u1 = snl - tau * v2 * t0;
    double sg = (ssmax < 0.0) ? -1.0 : 1.0;
    misc[hh * 2 + 0]     = (float)u0;
    misc[hh * 2 + 1]     = (float)u1;
    misc[4 + hh * 2 + 0] = (float)(sg * csr);
    misc[4 + hh * 2 + 1] = (float)(sg * snr);
    double s2 = fabs(ssmin);
    double rl = s2 - 0.15; if (rl < 0.0) rl = 0.0;
    aux += rl * rl;
  }
  aux_out[0] = (float)(aux * 0.1);
}

// ======================= RMS inv scale per row ==============================
__global__ __launch_bounds__(256) void rms_kernel(const float* __restrict__ tokens,
                                                  float* __restrict__ invrms)
{
  const int row = blockIdx.x, t = threadIdx.x;
  float4 v = *(const float4*)(tokens + (size_t)row * 1024 + t * 4);
  float s = v.x * v.x + v.y * v.y + v.z * v.z + v.w * v.w;
  for (int off = 32; off; off >>= 1) s += __shfl_down(s, off, 64);
  __shared__ float red[4];
  if ((t & 63) == 0) red[t >> 6] = s;
  __syncthreads();
  if (t == 0) {
    float tot = red[0] + red[1] + red[2] + red[3];
    invrms[row] = rsqrtf(tot * (1.0f / 1024.0f) + 1.1920929e-07f);
  }
}

// ============ fused RMS-scale + depthwise causal conv + bias ================
__global__ __launch_bounds__(256) void conv_kernel(const float* __restrict__ tokens,
                                                   const float* __restrict__ invrms,
                                                   const float* __restrict__ rms_w,
                                                   const float* __restrict__ conv_w,
                                                   const float* __restrict__ conv_b,
                                                   float* __restrict__ x2)
{
  const int row = blockIdx.x;          // b*1024 + n
  const int n   = row & 1023;
  const int ch0 = threadIdx.x * 4;
  float acc0 = 0.f, acc1 = 0.f, acc2 = 0.f, acc3 = 0.f;
  #pragma unroll
  for (int k = 0; k < 5; k++) {
    int nn = n - 4 + k;
    if (nn < 0) continue;
    int r2 = row - 4 + k;
    float ivr = invrms[r2];
    float4 tk4 = *(const float4*)(tokens + (size_t)r2 * 1024 + ch0);
    acc0 = fmaf(tk4.x * ivr, conv_w[(ch0 + 0) * 5 + k], acc0);
    acc1 = fmaf(tk4.y * ivr, conv_w[(ch0 + 1) * 5 + k], acc1);
    acc2 = fmaf(tk4.z * ivr, conv_w[(ch0 + 2) * 5 + k], acc2);
    acc3 = fmaf(tk4.w * ivr, conv_w[(ch0 + 3) * 5 + k], acc3);
  }
  float4 rw = *(const float4*)(rms_w + ch0);
  float4 cb = *(const float4*)(conv_b + ch0);
  float4 o;
  o.x = acc0 * rw.x + cb.x;
  o.y = acc1 * rw.y + cb.y;
  o.z = acc2 * rw.z + cb.z;
  o.w = acc3 * rw.w + cb.w;
  *(float4*)(x2 + (size_t)row * 1024 + ch0) = o;
}

// ============== generic 64xM-row x 128-col fp32 GEMM tile ===================
// C[row][col] = sum_k A[row][k]*Bm[col][k].  Per-block K extent = 128 (4 tiles
// of 32).  blockIdx.y shifts the K window (koffy), the col window (coffy) and
// a partial-output plane (poffy) so the same kernel serves both GEMMs at 256
// blocks (all CUs busy).
__global__ __launch_bounds__(256) void gemm_kernel(const float* __restrict__ A, int lda,
                                                   const float* __restrict__ Bm, int ldb,
                                                   float* __restrict__ C, int ldc,
                                                   int koffy, int coffy, int poffy)
{
  __shared__ __align__(16) float a_lds[32 * 64];    // [k][row]
  __shared__ __align__(16) float b_lds[32 * 128];   // [k][col]
  const int t  = threadIdx.x;
  const int rb = blockIdx.x * 64;
  const int kb = blockIdx.y * koffy;
  const int cb = blockIdx.y * coffy;
  C += (size_t)blockIdx.y * (size_t)poffy;
  const int tx = t & 31, ty = t >> 5;
  const int c0 = tx * 4, r0 = ty * 8;
  float acc[8][4];
  #pragma unroll
  for (int i = 0; i < 8; i++)
    #pragma unroll
    for (int j = 0; j < 4; j++) acc[i][j] = 0.0f;

  const int ra = t & 63,  kqa = (t >> 6) * 8;
  const int ob = t >> 1,  kqb = (t & 1) * 16;

  for (int kt = 0; kt < 4; kt++) {
    const int k0 = kb + kt * 32;
    {
      const float* ap = A + (size_t)(rb + ra) * lda + k0 + kqa;
      float4 a0 = *(const float4*)(ap);
      float4 a1 = *(const float4*)(ap + 4);
      a_lds[(kqa + 0) * 64 + ra] = a0.x;
      a_lds[(kqa + 1) * 64 + ra] = a0.y;
      a_lds[(kqa + 2) * 64 + ra] = a0.z;
      a_lds[(kqa + 3) * 64 + ra] = a0.w;
      a_lds[(kqa + 4) * 64 + ra] = a1.x;
      a_lds[(kqa + 5) * 64 + ra] = a1.y;
      a_lds[(kqa + 6) * 64 + ra] = a1.z;
      a_lds[(kqa + 7) * 64 + ra] = a1.w;
    }
    {
      const float* bp = Bm + (size_t)(cb + ob) * ldb + k0 + kqb;
      float4 b0 = *(const float4*)(bp);
      float4 b1 = *(const float4*)(bp + 4);
      float4 b2 = *(const float4*)(bp + 8);
      float4 b3 = *(const float4*)(bp + 12);
      b_lds[(kqb +  0) * 128 + ob] = b0.x;
      b_lds[(kqb +  1) * 128 + ob] = b0.y;
      b_lds[(kqb +  2) * 128 + ob] = b0.z;
      b_lds[(kqb +  3) * 128 + ob] = b0.w;
      b_lds[(kqb +  4) * 128 + ob] = b1.x;
      b_lds[(kqb +  5) * 128 + ob] = b1.y;
      b_lds[(kqb +  6) * 128 + ob] = b1.z;
      b_lds[(kqb +  7) * 128 + ob] = b1.w;
      b_lds[(kqb +  8) * 128 + ob] = b2.x;
      b_lds[(kqb +  9) * 128 + ob] = b2.y;
      b_lds[(kqb + 10) * 128 + ob] = b2.z;
      b_lds[(kqb + 11) * 128 + ob] = b2.w;
      b_lds[(kqb + 12) * 128 + ob] = b3.x;
      b_lds[(kqb + 13) * 128 + ob] = b3.y;
      b_lds[(kqb + 14) * 128 + ob] = b3.z;
      b_lds[(kqb + 15) * 128 + ob] = b3.w;
    }
    __syncthreads();
    #pragma unroll
    for (int k = 0; k < 32; k++) {
      float4 av0 = *(const float4*)(a_lds + k * 64 + r0);
      float4 av1 = *(const float4*)(a_lds + k * 64 + r0 + 4);
      float4 bv  = *(const float4*)(b_lds + k * 128 + c0);
      float ar[8] = {av0.x, av0.y, av0.z, av0.w, av1.x, av1.y, av1.z, av1.w};
      float br[4] = {bv.x, bv.y, bv.z, bv.w};
      #pragma unroll
      for (int i = 0; i < 8; i++)
        #pragma unroll
        for (int j = 0; j < 4; j++)
          acc[i][j] = fmaf(ar[i], br[j], acc[i][j]);
    }
    __syncthreads();
  }
  #pragma unroll
  for (int i = 0; i < 8; i++) {
    float4 o4; o4.x = acc[i][0]; o4.y = acc[i][1]; o4.z = acc[i][2]; o4.w = acc[i][3];
    *(float4*)(C + (size_t)(rb + r0 + i) * ldc + cb + c0) = o4;
  }
}

// ================= K-partial reduce + LayerNorm on q ========================
__global__ __launch_bounds__(128) void ln_kernel(const float* __restrict__ qpart,
                                                 const float* __restrict__ qln_w,
                                                 float* __restrict__ q)
{
  const int row = blockIdx.x, o = threadIdx.x;
  float v = 0.0f;
  #pragma unroll
  for (int g = 0; g < 8; g++) v += qpart[(size_t)g * (ROWS * 128) + (size_t)row * 128 + o];
  __shared__ float red[2];
  float s = v;
  for (int off = 32; off; off >>= 1) s += __shfl_down(s, off, 64);
  if ((o & 63) == 0) red[o >> 6] = s;
  __syncthreads();
  float mu  = (red[0] + red[1]) * (1.0f / 128.0f);
  float dv  = v - mu;
  float s2  = dv * dv;
  for (int off = 32; off; off >>= 1) s2 += __shfl_down(s2, off, 64);
  __syncthreads();
  if ((o & 63) == 0) red[o >> 6] = s2;
  __syncthreads();
  float var = (red[0] + red[1]) * (1.0f / 128.0f);
  q[(size_t)row * 128 + o] = dv * rsqrtf(var + 1e-5f) * qln_w[o];
}

// =============== tail: m_row/m_col, top-k, scores, gather ===================
__global__ __launch_bounds__(256) void tail_kernel(const float* __restrict__ sc,
                                                   const float* __restrict__ misc,
                                                   const float* __restrict__ core,
                                                   const float* __restrict__ memories,
                                                   float* __restrict__ out)
{
  __shared__ float s_row[512];      // [m][r]
  __shared__ float s_col[512];
  __shared__ int   tkbuf[4][32];    // wave w = (h<<1)|side
  __shared__ int   sel_i[2][32];
  __shared__ float sel_w[2][32];

  const int row = blockIdx.x;
  const int tid = threadIdx.x;
  const float* srow = sc + (size_t)row * 1024;
  for (int j = tid; j < 1024; j += 256) {   // sc[j] with j = (c*2+r)*256+m
    float v = srow[j];
    int m = j & 255;
    int r = j >> 8;
    if (r < 2) s_row[m * 2 + r]       = v;
    else       s_col[m * 2 + (r - 2)] = v;
  }
  __syncthreads();

  const int w = tid >> 6, lane = tid & 63;
  {
    // wave w: head = w>>1, side = w&1 -> top-32 of 256
    const int h = w >> 1, side = w & 1;
    const float v0 = misc[side * 4 + h * 2 + 0];
    const float v1 = misc[side * 4 + h * 2 + 1];
    const float* sb = side ? s_col : s_row;
    float vv[4];
    const int mb = lane * 4;
    #pragma unroll
    for (int i = 0; i < 4; i++)
      vv[i] = sb[(mb + i) * 2] * v0 + sb[(mb + i) * 2 + 1] * v1;
    float lm = vv[0]; int la = mb;
    #pragma unroll
    for (int i = 1; i < 4; i++) if (vv[i] > lm) { lm = vv[i]; la = mb + i; }
    for (int k = 0; k < 32; k++) {
      float cv = lm; int cm = la;
      for (int off = 32; off; off >>= 1) {
        float ov = __shfl_down(cv, off, 64);
        int   om = __shfl_down(cm, off, 64);
        if (ov > cv || (ov == cv && om < cm)) { cv = ov; cm = om; }
      }
      cm = __shfl(cm, 0, 64);
      if (lane == 0) tkbuf[w][k] = cm;
      if ((cm >> 2) == lane) {
        vv[cm & 3] = NEG_BIG;
        lm = vv[0]; la = mb;
        #pragma unroll
        for (int i = 1; i < 4; i++) if (vv[i] > lm) { lm = vv[i]; la = mb + i; }
      }
    }
  }
  __syncthreads();

  if (w < 2) {
    // wave w = head h: 32x32 candidate scores, top-32 of 1024.
    const int h = w;
    const float c00 = core[h * 4 + 0], c01 = core[h * 4 + 1];
    const float c10 = core[h * 4 + 2], c11 = core[h * 4 + 3];
    const int i  = lane >> 1;                 // candidate c = lane*16+t -> i = c>>5
    const int ri = tkbuf[h * 2 + 0][i];
    const float fr0 = s_row[ri * 2], fr1 = s_row[ri * 2 + 1];
    const float a0 = fr0 * c00 + fr1 * c10;
    const float a1 = fr0 * c01 + fr1 * c11;
    float sv[16];
    const int j0 = (lane & 1) * 16;
    #pragma unroll
    for (int t2 = 0; t2 < 16; t2++) {
      int cj = tkbuf[h * 2 + 1][j0 + t2];
      sv[t2] = a0 * s_col[cj * 2] + a1 * s_col[cj * 2 + 1];
    }
    float lm = sv[0]; int la = lane * 16;
    #pragma unroll
    for (int t2 = 1; t2 < 16; t2++) if (sv[t2] > lm) { lm = sv[t2]; la = lane * 16 + t2; }
    for (int k = 0; k < 32; k++) {
      float cv = lm; int cm = la;
      for (int off = 32; off; off >>= 1) {
        float ov = __shfl_down(cv, off, 64);
        int   om = __shfl_down(cm, off, 64);
        if (ov > cv || (ov == cv && om < cm)) { cv = ov; cm = om; }
      }
      cv = __shfl(cv, 0, 64);
      cm = __shfl(cm, 0, 64);
      if (lane == 0) {
        int ii = cm >> 5, jj = cm & 31;
        sel_i[h][k] = tkbuf[h * 2][ii] * 256 + tkbuf[h * 2 + 1][jj];
        sel_w[h][k] = 1.0f / (1.0f + expf(-cv));
      }
      if ((cm >> 4) == lane) {
        sv[cm & 15] = NEG_BIG;
        lm = sv[0]; la = lane * 16;
        #pragma unroll
        for (int t2 = 1; t2 < 16; t2++) if (sv[t2] > lm) { lm = sv[t2]; la = lane * 16 + t2; }
      }
    }
  }
  __syncthreads();

  // weighted gather-sum: out[b,n, h*512 + d]
  const int h2 = tid >> 7;
  const int d4 = (tid & 127);
  float ax = 0.f, ay = 0.f, az = 0.f, aw = 0.f;
  #pragma unroll 4
  for (int k = 0; k < 32; k++) {
    int   mi = sel_i[h2][k];
    float wg = sel_w[h2][k];
    float4 mv = *(const float4*)(memories + (size_t)mi * 512 + d4 * 4);
    ax = fmaf(wg, mv.x, ax);
    ay = fmaf(wg, mv.y, ay);
    az = fmaf(wg, mv.z, az);
    aw = fmaf(wg, mv.w, aw);
  }
  float4 o4; o4.x = ax; o4.y = ay; o4.z = az; o4.w = aw;
  ((float4*)out)[(size_t)row * 256 + tid] = o4;
}

// ============================== launcher ====================================
extern "C" void kernel_launch(void* const* d_in, const int* in_sizes, int n_in,
                              void* d_out, int out_size, void* d_ws, size_t ws_size,
                              hipStream_t stream) {
  const float* tokens = (const float*)d_in[0];
  const float* rms_w  = (const float*)d_in[1];
  const float* conv_w = (const float*)d_in[2];
  const float* conv_b = (const float*)d_in[3];
  const float* wq     = (const float*)d_in[4];
  const float* qln_w  = (const float*)d_in[5];
  const float* keys   = (const float*)d_in[6];
  const float* core   = (const float*)d_in[7];
  const float* mems   = (const float*)d_in[8];
  float* out = (float*)d_out;
  float* ws  = (float*)d_ws;

  // workspace layout (floats)
  float* misc   = ws;                          // 8
  float* invrms = ws + 16;                     // 2048
  float* x2     = ws + 4096;                   // 2048*1024
  float* qpart  = x2 + 2097152;                // 8 * 2048*128
  float* q      = qpart + 2097152;             // 2048*128
  float* sc     = x2;                          // alias: x2 dead after gemm1

  svd_kernel <<<1, 64, 0, stream>>>(core, misc, out + 2097152);
  rms_kernel <<<ROWS, 256, 0, stream>>>(tokens, invrms);
  conv_kernel<<<ROWS, 256, 0, stream>>>(tokens, invrms, rms_w, conv_w, conv_b, x2);
  // q_pre = x2 (2048x1024) * wq^T (1024x128), K split 8 ways -> partials
  gemm_kernel<<<dim3(32, 8), 256, 0, stream>>>(x2, 1024, wq, 1024,
                                               qpart, 128, 128, 0, ROWS * 128);
  ln_kernel  <<<ROWS, 128, 0, stream>>>(qpart, qln_w, q);
  // sc = q (2048x128) * keys^T (1024x128), N split 8 ways
  gemm_kernel<<<dim3(32, 8), 256, 0, stream>>>(q, 128, keys, 128,
                                               sc, 1024, 0, 128, 0);
  tail_kernel<<<ROWS, 256, 0, stream>>>(sc, misc, core, mems, out);
}